// Round 7
// baseline (975.420 us; speedup 1.0000x reference)
//
#include <hip/hip_runtime.h>
#include <hip/hip_bf16.h>

typedef __attribute__((ext_vector_type(8))) short  bf16x8;
typedef __attribute__((ext_vector_type(4))) short  s16x4;
typedef __attribute__((ext_vector_type(4))) float  f32x4;

#define LOG2E 1.44269504088896340736f
template<int N> struct ic { static constexpr int v = N; };

__device__ __forceinline__ unsigned short f2bf(float x) {
    union { float f; unsigned int u; } v; v.f = x;
    unsigned int u = v.u;
    u += 0x7fffu + ((u >> 16) & 1u);          // round-to-nearest-even
    return (unsigned short)(u >> 16);
}
__device__ __forceinline__ float fast_sigmoid(float x) {
    float e = __builtin_amdgcn_exp2f(-LOG2E * x);
    return __builtin_amdgcn_rcpf(1.0f + e);
}
__device__ __forceinline__ float fast_tanh(float x) {
    float e = __builtin_amdgcn_exp2f(2.0f * LOG2E * x);
    return 1.0f - 2.0f * __builtin_amdgcn_rcpf(1.0f + e);
}

// ---------------------------------------------------------------------------
// Pack [1024 x 256] fp32 weight into bf16 MFMA-B-fragment-major layout.
//   fid = w*64 + kk*8 + j ; dst[(fid*64+lane)*8+e] = bf16(W[R][k])
//   R = g*256 + w*32 + tn*16 + (lane&15), j = g*2+tn
//   k = kk*32 + 4*(lane>>4) + (e&3) + 16*(e>>2)
// ---------------------------------------------------------------------------
__global__ void pack_w_big(const float* __restrict__ W, unsigned short* __restrict__ dst) {
    int idx  = blockIdx.x * 256 + threadIdx.x;   // 0..32767
    int lane = idx & 63;
    int fid  = idx >> 6;                         // 0..511
    int j    = fid & 7;
    int kk   = (fid >> 3) & 7;
    int w    = fid >> 6;
    int g    = j >> 1, tn = j & 1;
    int R    = g * 256 + w * 32 + tn * 16 + (lane & 15);
    int kb   = kk * 32 + 4 * (lane >> 4);
    const float* src = W + (size_t)R * 256 + kb;
    union { unsigned short s[8]; uint4 v; } u;
#pragma unroll
    for (int e = 0; e < 8; ++e) {
        int k = (e & 3) + 16 * (e >> 2);
        u.s[e] = f2bf(src[k]);
    }
    *(uint4*)(dst + (size_t)idx * 8) = u.v;
}

// W_out [128 x 256]: fid = wv*8 + kk, R = wv*16 + (lane&15)
__global__ void pack_w_out(const float* __restrict__ W, unsigned short* __restrict__ dst) {
    int idx  = blockIdx.x * 256 + threadIdx.x;   // 0..4095
    int lane = idx & 63;
    int fid  = idx >> 6;
    int kk   = fid & 7;
    int wv   = fid >> 3;
    int R    = wv * 16 + (lane & 15);
    int kb   = kk * 32 + 4 * (lane >> 4);
    const float* src = W + (size_t)R * 256 + kb;
    union { unsigned short s[8]; uint4 v; } u;
#pragma unroll
    for (int e = 0; e < 8; ++e) {
        int k = (e & 3) + 16 * (e >> 2);
        u.s[e] = f2bf(src[k]);
    }
    *(uint4*)(dst + (size_t)idx * 8) = u.v;
}

// ---------------------------------------------------------------------------
// Replicate the streamed kk5..7 region of packed Whh into ncopies private
// copies. Per copy: [w][kk'][j][lane][8] shorts, kk' = kk-5, size 98304
// shorts (192 KB). One uint4 (8 shorts) per thread.
// ---------------------------------------------------------------------------
__global__ void replicate_stream(const unsigned short* __restrict__ Whh_p,
                                 unsigned short* __restrict__ rep) {
    int gidx = blockIdx.x * 256 + threadIdx.x;   // copy*12288 + q
    int q    = gidx % 12288;
    int c    = gidx / 12288;
    int lane = q & 63;
    int f    = q >> 6;          // 0..191 = w*24 + kkp*8 + j
    int j    = f & 7;
    int kkp  = (f >> 3) % 3;
    int w    = f / 24;
    const uint4* src = (const uint4*)(Whh_p + (((size_t)w * 64 + (5 + kkp) * 8 + j) * 64 + lane) * 8);
    uint4* dst = (uint4*)(rep + (size_t)c * 98304 + ((size_t)q) * 8);
    *dst = *src;
}

// ---------------------------------------------------------------------------
// Gates-only persistent LSTM. 128 blocks x 512 thr (8 waves). Wave w owns
// gate strip [w*32,+32) x {i,f,g,o}. h_t (bf16) written to H (= d_out, in
// place; y computed later by out_gemm). Whh: kk0..3 register-resident,
// kk4 LDS-parked, kk5..7 streamed from a PER-BLOCK PRIVATE copy (rep) via
// global_load_lds ring with counted vmcnt(4); next-step kk5 prefetch crosses
// a raw s_barrier.
// ---------------------------------------------------------------------------
__global__ __launch_bounds__(512) __attribute__((amdgpu_waves_per_eu(2, 2)))
void lstm_gates(const float* __restrict__ C,
                const unsigned short* __restrict__ Wih_p,
                const unsigned short* __restrict__ Whh_p,
                const unsigned short* __restrict__ rep,
                const float* __restrict__ b_ih,
                const float* __restrict__ b_hh,
                unsigned short* __restrict__ H,
                int T, int Btot, int ncopies)
{
    __shared__ short hbuf[2][4096];     // 16 KB h double-buffer
    __shared__ short park[8][8][512];   // 64 KB kk4 B-frags (per wave)
    __shared__ short ring[8][8][512];   // 64 KB stream ring: slot j <-> frag j

    const int tid  = threadIdx.x;
    const int l    = tid & 63;
    const int wid  = tid >> 6;
    const int l15  = l & 15;
    const int g4   = l >> 4;
    const int row0 = blockIdx.x * 16;

    const unsigned short* wib = Wih_p + (size_t)wid * 32768;
    const unsigned short* whb = Whh_p + (size_t)wid * 32768;
    // private streamed region for this block's wave wid
    const unsigned short* wstr = rep + (size_t)(blockIdx.x % ncopies) * 98304
                                     + (size_t)wid * 12288;

    // ---- stage C tile -> hbuf[0] (bf16, swizzled 8B slots) ----
    {
        int r  = tid >> 5;
        int cb = tid & 31;
        const float* src = C + (size_t)(row0 + r) * 256 + cb * 8;
        float4 f0 = *(const float4*)(src);
        float4 f1 = *(const float4*)(src + 4);
        int m  = 9 * (r & 7);
        int s0 = cb * 2;
        short* hb = hbuf[0] + r * 256;
        union { unsigned short s[4]; unsigned long long v; } p0, p1;
        p0.s[0] = f2bf(f0.x); p0.s[1] = f2bf(f0.y); p0.s[2] = f2bf(f0.z); p0.s[3] = f2bf(f0.w);
        p1.s[0] = f2bf(f1.x); p1.s[1] = f2bf(f1.y); p1.s[2] = f2bf(f1.z); p1.s[3] = f2bf(f1.w);
        *(unsigned long long*)(hb + ((s0 ^ m) * 4))       = p0.v;
        *(unsigned long long*)(hb + (((s0 + 1) ^ m) * 4)) = p1.v;
    }

    // park staging (shared base Whh_p, one-time) and first ring fill (private)
    auto issueP = [&](int j) {
        const unsigned short* src = whb + (((size_t)4 * 8 + j) * 64 + l) * 8;
        __builtin_amdgcn_global_load_lds(
            (const __attribute__((address_space(1))) void*)src,
            (__attribute__((address_space(3))) void*)&park[wid][j][0], 16, 0, 0);
    };
    auto issueS = [&](int kkp, int j) {   // kkp in {0,1,2} = kk-5
        const unsigned short* src = wstr + ((size_t)(kkp * 8 + j) * 64 + l) * 8;
        __builtin_amdgcn_global_load_lds(
            (const __attribute__((address_space(1))) void*)src,
            (__attribute__((address_space(3))) void*)&ring[wid][j][0], 16, 0, 0);
    };
#pragma unroll
    for (int j = 0; j < 8; ++j) issueP(j);
#pragma unroll
    for (int j = 0; j < 8; ++j) issueS(0, j);

    // A-frag loader: row = l&15, k = kk*32 + 4*(l>>4) + {0..3,16..19}
    const int msw = 9 * (l15 & 7);
    auto loadA = [&](const short* buf, int kk) -> bf16x8 {
        int slo = kk * 8 + g4;
        const short* base = buf + l15 * 256;
        s16x4 lo = *(const s16x4*)(base + ((slo ^ msw) * 4));
        s16x4 hi = *(const s16x4*)(base + (((slo + 4) ^ msw) * 4));
        bf16x8 a;
        a[0] = lo[0]; a[1] = lo[1]; a[2] = lo[2]; a[3] = lo[3];
        a[4] = hi[0]; a[5] = hi[1]; a[6] = hi[2]; a[7] = hi[3];
        return a;
    };
    auto loadB = [&](const unsigned short* wb, int kk, int j) -> bf16x8 {
        return *(const bf16x8*)(wb + (((size_t)kk * 8 + j) * 64 + l) * 8);
    };

    __syncthreads();   // C tile + park + ring(kk5) staged (one-time drain)

    // ---- acc = x_gates = C @ Wih^T + b_ih + b_hh ----
    f32x4 acc[8];
#pragma unroll
    for (int j = 0; j < 8; ++j) acc[j] = (f32x4){0.f, 0.f, 0.f, 0.f};
#pragma unroll
    for (int kk = 0; kk < 8; ++kk) {
        bf16x8 a = loadA(hbuf[0], kk);
#pragma unroll
        for (int j = 0; j < 8; ++j)
            acc[j] = __builtin_amdgcn_mfma_f32_16x16x32_bf16(a, loadB(wib, kk, j), acc[j], 0, 0, 0);
    }
#pragma unroll
    for (int j = 0; j < 8; ++j) {
        int g = j >> 1, tn = j & 1;
        int col = g * 256 + wid * 32 + tn * 16 + l15;
        float bias = b_ih[col] + b_hh[col];
        acc[j] = acc[j] + bias;
    }
    // pack x_gates to bf16 (persistent, 16 regs)
    unsigned xgp[16];
#pragma unroll
    for (int j = 0; j < 8; ++j) {
        xgp[2 * j]     = (unsigned)f2bf(acc[j][0]) | ((unsigned)f2bf(acc[j][1]) << 16);
        xgp[2 * j + 1] = (unsigned)f2bf(acc[j][2]) | ((unsigned)f2bf(acc[j][3]) << 16);
    }
    auto xgu = [&](int j) -> f32x4 {
        union { unsigned u; float f; } c0, c1, c2, c3;
        unsigned u0 = xgp[2 * j], u1 = xgp[2 * j + 1];
        c0.u = u0 << 16; c1.u = u0 & 0xffff0000u;
        c2.u = u1 << 16; c3.u = u1 & 0xffff0000u;
        return (f32x4){c0.f, c1.f, c2.f, c3.f};
    };

    // ---- Whh kk0..3 register-resident ----
    bf16x8 whr[4][8];
#pragma unroll
    for (int kk = 0; kk < 4; ++kk)
#pragma unroll
        for (int j = 0; j < 8; ++j) whr[kk][j] = loadB(whb, kk, j);

    float cst[8];
#pragma unroll
    for (int i = 0; i < 8; ++i) cst[i] = 0.f;

    // cell update -> h into nxtb (swz LDS) + H global (plain rows)
    auto update_write = [&](short* nxtb, unsigned short* hst) {
#pragma unroll
        for (int tn = 0; tn < 2; ++tn) {
#pragma unroll
            for (int rr = 0; rr < 4; ++rr) {
                float iv = fast_sigmoid(acc[0 + tn][rr]);
                float fv = fast_sigmoid(acc[2 + tn][rr]);
                float gv = fast_tanh(acc[4 + tn][rr]);
                float ov = fast_sigmoid(acc[6 + tn][rr]);
                float cn = fv * cst[tn * 4 + rr] + iv * gv;
                cst[tn * 4 + rr] = cn;
                float hn = ov * fast_tanh(cn);
                unsigned short hb = f2bf(hn);
                int row = 4 * g4 + rr;
                int col = wid * 32 + tn * 16 + l15;
                int ps  = (col >> 2) ^ (9 * (row & 7));
                nxtb[row * 256 + ps * 4 + (col & 3)] = (short)hb;
                hst[(size_t)row * 256 + col] = hb;
            }
        }
    };

    // ---- t = 1: gates = x_gates (h0 = 0); h1 -> hbuf[1], H[0] ----
    update_write(hbuf[1], H + (size_t)row0 * 256);
    __syncthreads();

    // ---- phase lambdas ----
    auto phaseR0 = [&](const short* curb) {
        bf16x8 a = loadA(curb, 0);
#pragma unroll
        for (int j = 0; j < 8; ++j)
            acc[j] = __builtin_amdgcn_mfma_f32_16x16x32_bf16(a, whr[0][j], xgu(j), 0, 0, 0);
    };
    auto phaseR = [&](auto KK, const short* curb) {
        constexpr int kk = decltype(KK)::v;
        bf16x8 a = loadA(curb, kk);
#pragma unroll
        for (int j = 0; j < 8; ++j)
            acc[j] = __builtin_amdgcn_mfma_f32_16x16x32_bf16(a, whr[kk][j], acc[j], 0, 0, 0);
    };
    auto phaseP = [&](const short* curb) {
        bf16x8 a = loadA(curb, 4);
#pragma unroll
        for (int j = 0; j < 8; ++j) {
            bf16x8 b = *(const bf16x8*)&park[wid][j][l * 8];
            acc[j] = __builtin_amdgcn_mfma_f32_16x16x32_bf16(a, b, acc[j], 0, 0, 0);
        }
    };
    auto phaseS = [&](auto KK, auto NXP, const short* curb) {
        constexpr int kk  = decltype(KK)::v;     // consumed slice (5,6,7)
        constexpr int nxp = decltype(NXP)::v;    // next slice kk' (kk-5) to issue
        bf16x8 a = loadA(curb, kk);
        asm volatile("s_waitcnt vmcnt(4)" ::: "memory");
#pragma unroll
        for (int j = 0; j < 4; ++j) {
            bf16x8 b = *(const bf16x8*)&ring[wid][j][l * 8];
            acc[j] = __builtin_amdgcn_mfma_f32_16x16x32_bf16(a, b, acc[j], 0, 0, 0);
        }
#pragma unroll
        for (int j = 0; j < 4; ++j) issueS(nxp, j);
        asm volatile("s_waitcnt vmcnt(4)" ::: "memory");
#pragma unroll
        for (int j = 4; j < 8; ++j) {
            bf16x8 b = *(const bf16x8*)&ring[wid][j][l * 8];
            acc[j] = __builtin_amdgcn_mfma_f32_16x16x32_bf16(a, b, acc[j], 0, 0, 0);
        }
#pragma unroll
        for (int j = 4; j < 8; ++j) issueS(nxp, j);
    };

    // ---- main loop: compute h_t for t = 2..T ----
    for (int t = 2; t <= T; ++t) {
        const short* curb = hbuf[(t - 1) & 1];
        short*       nxtb = hbuf[t & 1];

        phaseR0(curb);
        phaseR(ic<1>{}, curb);
        phaseR(ic<2>{}, curb);
        phaseR(ic<3>{}, curb);
        phaseP(curb);
        phaseS(ic<5>{}, ic<1>{}, curb);   // consume kk5, prefetch kk6
        phaseS(ic<6>{}, ic<2>{}, curb);   // consume kk6, prefetch kk7
        phaseS(ic<7>{}, ic<0>{}, curb);   // consume kk7, prefetch next-step kk5

        update_write(nxtb, H + ((size_t)(t - 1) * Btot + row0) * 256);

        // raw barrier: h LDS writes visible; ring prefetch stays in flight
        asm volatile("s_waitcnt lgkmcnt(0)" ::: "memory");
        __builtin_amdgcn_sched_barrier(0);
        __builtin_amdgcn_s_barrier();
    }
}

// ---------------------------------------------------------------------------
// Y[s][b][:] = H[s][b][:] @ Wout^T + b_out, IN PLACE (H bf16 row = 512 B =
// Y f32 row). Each wave reads only its own 32 rows then overwrites them.
// ---------------------------------------------------------------------------
__global__ __launch_bounds__(512) void out_gemm(
    const unsigned short* __restrict__ Wout_p,
    const float* __restrict__ b_out,
    float* __restrict__ Y)
{
    const int tid = threadIdx.x;
    const int l   = tid & 63;
    const int w   = tid >> 6;
    const int l15 = l & 15;
    const int g4  = l >> 4;
    const size_t rw0 = (size_t)blockIdx.x * 256 + w * 32;
    const unsigned short* Hp = (const unsigned short*)Y;

    bf16x8 a[2][8];
#pragma unroll
    for (int rt = 0; rt < 2; ++rt)
#pragma unroll
        for (int kk = 0; kk < 8; ++kk) {
            const unsigned short* src = Hp + (rw0 + rt * 16 + l15) * 256 + kk * 32 + 4 * g4;
            s16x4 lo = *(const s16x4*)(src);
            s16x4 hi = *(const s16x4*)(src + 16);
            bf16x8 v;
            v[0] = lo[0]; v[1] = lo[1]; v[2] = lo[2]; v[3] = lo[3];
            v[4] = hi[0]; v[5] = hi[1]; v[6] = hi[2]; v[7] = hi[3];
            a[rt][kk] = v;
        }

    f32x4 acc[2][8];
#pragma unroll
    for (int rt = 0; rt < 2; ++rt)
#pragma unroll
        for (int wv = 0; wv < 8; ++wv) acc[rt][wv] = (f32x4){0.f, 0.f, 0.f, 0.f};

#pragma unroll
    for (int kk = 0; kk < 8; ++kk)
#pragma unroll
        for (int wv = 0; wv < 8; ++wv) {
            bf16x8 wf = *(const bf16x8*)(Wout_p + ((size_t)(wv * 8 + kk) * 64 + l) * 8);
            acc[0][wv] = __builtin_amdgcn_mfma_f32_16x16x32_bf16(a[0][kk], wf, acc[0][wv], 0, 0, 0);
            acc[1][wv] = __builtin_amdgcn_mfma_f32_16x16x32_bf16(a[1][kk], wf, acc[1][wv], 0, 0, 0);
        }

#pragma unroll
    for (int wv = 0; wv < 8; ++wv) {
        float by = b_out[wv * 16 + l15];
#pragma unroll
        for (int rt = 0; rt < 2; ++rt)
#pragma unroll
            for (int i = 0; i < 4; ++i)
                Y[(rw0 + rt * 16 + 4 * g4 + i) * 128 + wv * 16 + l15] = acc[rt][wv][i] + by;
    }
}

extern "C" void kernel_launch(void* const* d_in, const int* in_sizes, int n_in,
                              void* d_out, int out_size, void* d_ws, size_t ws_size,
                              hipStream_t stream) {
    const float* C     = (const float*)d_in[0];
    const float* W_ih  = (const float*)d_in[1];
    const float* W_hh  = (const float*)d_in[2];
    const float* b_ih  = (const float*)d_in[3];
    const float* b_hh  = (const float*)d_in[4];
    const float* W_out = (const float*)d_in[5];
    const float* b_out = (const float*)d_in[6];

    const int H    = 256;
    const int Btot = in_sizes[0] / H;     // 2048
    const int O    = in_sizes[5] / H;     // 128
    const int T    = out_size / (Btot * O);

    char* ws = (char*)d_ws;
    unsigned short* Whh_p  = (unsigned short*)(ws);                 // 512 KB
    unsigned short* Wih_p  = (unsigned short*)(ws + (512 << 10));   // 512 KB
    unsigned short* Wout_p = (unsigned short*)(ws + (1024 << 10));  // 64 KB
    unsigned short* rep    = (unsigned short*)(ws + (1088 << 10));  // copies

    const size_t copy_bytes = 196608;     // 192 KB
    size_t avail = (ws_size > (1088u << 10)) ? ws_size - (1088u << 10) : 0;
    int ncopies = (int)(avail / copy_bytes);
    if (ncopies > 128) ncopies = 128;
    if (ncopies < 1)   ncopies = 1;       // degenerate: reuse region 0 pattern
    // if even 1 copy doesn't fit, fall back to reading Whh_p directly
    bool use_rep = ncopies >= 1 && avail >= copy_bytes;

    hipLaunchKernelGGL(pack_w_big, dim3(128), dim3(256), 0, stream, W_hh, Whh_p);
    hipLaunchKernelGGL(pack_w_big, dim3(128), dim3(256), 0, stream, W_ih, Wih_p);
    hipLaunchKernelGGL(pack_w_out, dim3(16),  dim3(256), 0, stream, W_out, Wout_p);
    if (use_rep) {
        hipLaunchKernelGGL(replicate_stream, dim3(ncopies * 48), dim3(256), 0, stream,
                           Whh_p, rep);
    } else {
        // shouldn't happen with normal ws_size; alias rep to packed kk5..7
        rep = Whh_p;  // layout mismatch avoided by ncopies=1 path below
    }
    if (!use_rep) {
        // build a single in-place copy at Wih_p end is impossible; just
        // replicate once into Wout_p tail region is too small -> use Whh_p
        // directly is layout-incompatible. In practice ws_size >> 1.3 MB.
        ncopies = 1;
    }
    hipLaunchKernelGGL(lstm_gates, dim3(Btot / 16), dim3(512), 0, stream,
                       C, Wih_p, Whh_p, rep, b_ih, b_hh,
                       (unsigned short*)d_out, T, Btot, ncopies);
    hipLaunchKernelGGL(out_gemm, dim3((T * Btot) / 256), dim3(512), 0, stream,
                       Wout_p, b_out, (float*)d_out);
}

// Round 9
// 947.423 us; speedup vs baseline: 1.0296x; 1.0296x over previous
//
#include <hip/hip_runtime.h>
#include <hip/hip_bf16.h>

typedef __attribute__((ext_vector_type(8))) short  bf16x8;
typedef __attribute__((ext_vector_type(4))) short  s16x4;
typedef __attribute__((ext_vector_type(4))) float  f32x4;
typedef __attribute__((ext_vector_type(4))) unsigned int u32x4;

#define LOG2E 1.44269504088896340736f
template<int N> struct ic { static constexpr int v = N; };

__device__ __forceinline__ unsigned short f2bf(float x) {
    union { float f; unsigned int u; } v; v.f = x;
    unsigned int u = v.u;
    u += 0x7fffu + ((u >> 16) & 1u);          // round-to-nearest-even
    return (unsigned short)(u >> 16);
}
__device__ __forceinline__ float fast_sigmoid(float x) {
    float e = __builtin_amdgcn_exp2f(-LOG2E * x);
    return __builtin_amdgcn_rcpf(1.0f + e);
}
__device__ __forceinline__ float fast_tanh(float x) {
    float e = __builtin_amdgcn_exp2f(2.0f * LOG2E * x);
    return 1.0f - 2.0f * __builtin_amdgcn_rcpf(1.0f + e);
}

// ---------------------------------------------------------------------------
// Pack [1024 x 256] fp32 weight into bf16 MFMA-B-fragment-major layout.
//   fid = w*64 + kk*8 + j ; dst[(fid*64+lane)*8+e] = bf16(W[R][k])
//   R = g*256 + w*32 + tn*16 + (lane&15), j = g*2+tn
//   k = kk*32 + 4*(lane>>4) + (e&3) + 16*(e>>2)
// ---------------------------------------------------------------------------
__global__ void pack_w_big(const float* __restrict__ W, unsigned short* __restrict__ dst) {
    int idx  = blockIdx.x * 256 + threadIdx.x;   // 0..32767
    int lane = idx & 63;
    int fid  = idx >> 6;                         // 0..511
    int j    = fid & 7;
    int kk   = (fid >> 3) & 7;
    int w    = fid >> 6;
    int g    = j >> 1, tn = j & 1;
    int R    = g * 256 + w * 32 + tn * 16 + (lane & 15);
    int kb   = kk * 32 + 4 * (lane >> 4);
    const float* src = W + (size_t)R * 256 + kb;
    union { unsigned short s[8]; u32x4 v; } u;
#pragma unroll
    for (int e = 0; e < 8; ++e) {
        int k = (e & 3) + 16 * (e >> 2);
        u.s[e] = f2bf(src[k]);
    }
    *(u32x4*)(dst + (size_t)idx * 8) = u.v;
}

// W_out [128 x 256]: fid = wv*8 + kk, R = wv*16 + (lane&15)
__global__ void pack_w_out(const float* __restrict__ W, unsigned short* __restrict__ dst) {
    int idx  = blockIdx.x * 256 + threadIdx.x;   // 0..4095
    int lane = idx & 63;
    int fid  = idx >> 6;
    int kk   = fid & 7;
    int wv   = fid >> 3;
    int R    = wv * 16 + (lane & 15);
    int kb   = kk * 32 + 4 * (lane >> 4);
    const float* src = W + (size_t)R * 256 + kb;
    union { unsigned short s[8]; u32x4 v; } u;
#pragma unroll
    for (int e = 0; e < 8; ++e) {
        int k = (e & 3) + 16 * (e >> 2);
        u.s[e] = f2bf(src[k]);
    }
    *(u32x4*)(dst + (size_t)idx * 8) = u.v;
}

// ---------------------------------------------------------------------------
// Replicate the streamed kk5..7 region of packed Whh into ncopies copies.
// Per copy: [w][kk'][j][lane][8] shorts, kk' = kk-5, 98304 shorts (192 KB).
// NT stores: don't pollute L2 at setup; each reader XCD pulls its own copy.
// ---------------------------------------------------------------------------
__global__ void replicate_stream(const unsigned short* __restrict__ Whh_p,
                                 unsigned short* __restrict__ rep) {
    int gidx = blockIdx.x * 256 + threadIdx.x;   // copy*12288 + q
    int q    = gidx % 12288;
    int c    = gidx / 12288;
    int lane = q & 63;
    int f    = q >> 6;          // 0..191 = w*24 + kkp*8 + j
    int j    = f & 7;
    int kkp  = (f >> 3) % 3;
    int w    = f / 24;
    const u32x4* src = (const u32x4*)(Whh_p + (((size_t)w * 64 + (5 + kkp) * 8 + j) * 64 + lane) * 8);
    u32x4* dst = (u32x4*)(rep + (size_t)c * 98304 + ((size_t)q) * 8);
    u32x4 v = *src;
    __builtin_nontemporal_store(v, dst);
}

// ---------------------------------------------------------------------------
// Gates-only persistent LSTM. 128 blocks x 512 thr (8 waves). Wave w owns
// gate strip [w*32,+32) x {i,f,g,o}. h_t (bf16) written NT to H (= d_out,
// in place; y computed later by out_gemm). Whh: kk0..3 register-resident,
// kk4 LDS-parked, kk5..7 streamed from a 2-reader-shared L2-resident copy
// via global_load_lds ring with counted vmcnt(4).
// ---------------------------------------------------------------------------
__global__ __launch_bounds__(512) __attribute__((amdgpu_waves_per_eu(2, 2)))
void lstm_gates(const float* __restrict__ C,
                const unsigned short* __restrict__ Wih_p,
                const unsigned short* __restrict__ Whh_p,
                const unsigned short* __restrict__ rep,
                const float* __restrict__ b_ih,
                const float* __restrict__ b_hh,
                unsigned short* __restrict__ H,
                int T, int Btot, int ncopies)
{
    __shared__ short hbuf[2][4096];     // 16 KB h double-buffer
    __shared__ short park[8][8][512];   // 64 KB kk4 B-frags (per wave)
    __shared__ short ring[8][8][512];   // 64 KB stream ring: slot j <-> frag j

    const int tid  = threadIdx.x;
    const int l    = tid & 63;
    const int wid  = tid >> 6;
    const int l15  = l & 15;
    const int g4   = l >> 4;
    const int row0 = blockIdx.x * 16;

    const unsigned short* wib = Wih_p + (size_t)wid * 32768;
    const unsigned short* whb = Whh_p + (size_t)wid * 32768;
    // streamed region: copy shared by 2 same-XCD blocks (bid, bid+64)
    const unsigned short* wstr = rep + (size_t)(blockIdx.x % ncopies) * 98304
                                     + (size_t)wid * 12288;

    // ---- stage C tile -> hbuf[0] (bf16, swizzled 8B slots) ----
    {
        int r  = tid >> 5;
        int cb = tid & 31;
        const float* src = C + (size_t)(row0 + r) * 256 + cb * 8;
        float4 f0 = *(const float4*)(src);
        float4 f1 = *(const float4*)(src + 4);
        int m  = 9 * (r & 7);
        int s0 = cb * 2;
        short* hb = hbuf[0] + r * 256;
        union { unsigned short s[4]; unsigned long long v; } p0, p1;
        p0.s[0] = f2bf(f0.x); p0.s[1] = f2bf(f0.y); p0.s[2] = f2bf(f0.z); p0.s[3] = f2bf(f0.w);
        p1.s[0] = f2bf(f1.x); p1.s[1] = f2bf(f1.y); p1.s[2] = f2bf(f1.z); p1.s[3] = f2bf(f1.w);
        *(unsigned long long*)(hb + ((s0 ^ m) * 4))       = p0.v;
        *(unsigned long long*)(hb + (((s0 + 1) ^ m) * 4)) = p1.v;
    }

    auto issueP = [&](int j) {
        const unsigned short* src = whb + (((size_t)4 * 8 + j) * 64 + l) * 8;
        __builtin_amdgcn_global_load_lds(
            (const __attribute__((address_space(1))) void*)src,
            (__attribute__((address_space(3))) void*)&park[wid][j][0], 16, 0, 0);
    };
    auto issueS = [&](int kkp, int j) {   // kkp in {0,1,2} = kk-5
        const unsigned short* src = wstr + ((size_t)(kkp * 8 + j) * 64 + l) * 8;
        __builtin_amdgcn_global_load_lds(
            (const __attribute__((address_space(1))) void*)src,
            (__attribute__((address_space(3))) void*)&ring[wid][j][0], 16, 0, 0);
    };
#pragma unroll
    for (int j = 0; j < 8; ++j) issueP(j);
#pragma unroll
    for (int j = 0; j < 8; ++j) issueS(0, j);

    // A-frag loader: row = l&15, k = kk*32 + 4*(l>>4) + {0..3,16..19}
    const int msw = 9 * (l15 & 7);
    auto loadA = [&](const short* buf, int kk) -> bf16x8 {
        int slo = kk * 8 + g4;
        const short* base = buf + l15 * 256;
        s16x4 lo = *(const s16x4*)(base + ((slo ^ msw) * 4));
        s16x4 hi = *(const s16x4*)(base + (((slo + 4) ^ msw) * 4));
        bf16x8 a;
        a[0] = lo[0]; a[1] = lo[1]; a[2] = lo[2]; a[3] = lo[3];
        a[4] = hi[0]; a[5] = hi[1]; a[6] = hi[2]; a[7] = hi[3];
        return a;
    };
    auto loadB = [&](const unsigned short* wb, int kk, int j) -> bf16x8 {
        return *(const bf16x8*)(wb + (((size_t)kk * 8 + j) * 64 + l) * 8);
    };

    __syncthreads();   // C tile + park + ring(kk5) staged (one-time drain)

    // ---- acc = x_gates = C @ Wih^T + b_ih + b_hh ----
    f32x4 acc[8];
#pragma unroll
    for (int j = 0; j < 8; ++j) acc[j] = (f32x4){0.f, 0.f, 0.f, 0.f};
#pragma unroll
    for (int kk = 0; kk < 8; ++kk) {
        bf16x8 a = loadA(hbuf[0], kk);
#pragma unroll
        for (int j = 0; j < 8; ++j)
            acc[j] = __builtin_amdgcn_mfma_f32_16x16x32_bf16(a, loadB(wib, kk, j), acc[j], 0, 0, 0);
    }
#pragma unroll
    for (int j = 0; j < 8; ++j) {
        int g = j >> 1, tn = j & 1;
        int col = g * 256 + wid * 32 + tn * 16 + l15;
        float bias = b_ih[col] + b_hh[col];
        acc[j] = acc[j] + bias;
    }
    // pack x_gates to bf16 (persistent, 16 regs)
    unsigned xgp[16];
#pragma unroll
    for (int j = 0; j < 8; ++j) {
        xgp[2 * j]     = (unsigned)f2bf(acc[j][0]) | ((unsigned)f2bf(acc[j][1]) << 16);
        xgp[2 * j + 1] = (unsigned)f2bf(acc[j][2]) | ((unsigned)f2bf(acc[j][3]) << 16);
    }
    auto xgu = [&](int j) -> f32x4 {
        union { unsigned u; float f; } c0, c1, c2, c3;
        unsigned u0 = xgp[2 * j], u1 = xgp[2 * j + 1];
        c0.u = u0 << 16; c1.u = u0 & 0xffff0000u;
        c2.u = u1 << 16; c3.u = u1 & 0xffff0000u;
        return (f32x4){c0.f, c1.f, c2.f, c3.f};
    };

    // ---- Whh kk0..3 register-resident ----
    bf16x8 whr[4][8];
#pragma unroll
    for (int kk = 0; kk < 4; ++kk)
#pragma unroll
        for (int j = 0; j < 8; ++j) whr[kk][j] = loadB(whb, kk, j);

    float cst[8];
#pragma unroll
    for (int i = 0; i < 8; ++i) cst[i] = 0.f;

    // cell update -> h into nxtb (swz LDS) + H global (NT, keep L2 clean)
    auto update_write = [&](short* nxtb, unsigned short* hst) {
#pragma unroll
        for (int tn = 0; tn < 2; ++tn) {
#pragma unroll
            for (int rr = 0; rr < 4; ++rr) {
                float iv = fast_sigmoid(acc[0 + tn][rr]);
                float fv = fast_sigmoid(acc[2 + tn][rr]);
                float gv = fast_tanh(acc[4 + tn][rr]);
                float ov = fast_sigmoid(acc[6 + tn][rr]);
                float cn = fv * cst[tn * 4 + rr] + iv * gv;
                cst[tn * 4 + rr] = cn;
                float hn = ov * fast_tanh(cn);
                unsigned short hb = f2bf(hn);
                int row = 4 * g4 + rr;
                int col = wid * 32 + tn * 16 + l15;
                int ps  = (col >> 2) ^ (9 * (row & 7));
                nxtb[row * 256 + ps * 4 + (col & 3)] = (short)hb;
                __builtin_nontemporal_store(hb, hst + (size_t)row * 256 + col);
            }
        }
    };

    // ---- t = 1: gates = x_gates (h0 = 0); h1 -> hbuf[1], H[0] ----
    update_write(hbuf[1], H + (size_t)row0 * 256);
    __syncthreads();

    // ---- phase lambdas ----
    auto phaseR0 = [&](const short* curb) {
        bf16x8 a = loadA(curb, 0);
#pragma unroll
        for (int j = 0; j < 8; ++j)
            acc[j] = __builtin_amdgcn_mfma_f32_16x16x32_bf16(a, whr[0][j], xgu(j), 0, 0, 0);
    };
    auto phaseR = [&](auto KK, const short* curb) {
        constexpr int kk = decltype(KK)::v;
        bf16x8 a = loadA(curb, kk);
#pragma unroll
        for (int j = 0; j < 8; ++j)
            acc[j] = __builtin_amdgcn_mfma_f32_16x16x32_bf16(a, whr[kk][j], acc[j], 0, 0, 0);
    };
    auto phaseP = [&](const short* curb) {
        bf16x8 a = loadA(curb, 4);
#pragma unroll
        for (int j = 0; j < 8; ++j) {
            bf16x8 b = *(const bf16x8*)&park[wid][j][l * 8];
            acc[j] = __builtin_amdgcn_mfma_f32_16x16x32_bf16(a, b, acc[j], 0, 0, 0);
        }
    };
    auto phaseS = [&](auto KK, auto NXP, const short* curb) {
        constexpr int kk  = decltype(KK)::v;     // consumed slice (5,6,7)
        constexpr int nxp = decltype(NXP)::v;    // next slice kk' (kk-5) to issue
        bf16x8 a = loadA(curb, kk);
        asm volatile("s_waitcnt vmcnt(4)" ::: "memory");
#pragma unroll
        for (int j = 0; j < 4; ++j) {
            bf16x8 b = *(const bf16x8*)&ring[wid][j][l * 8];
            acc[j] = __builtin_amdgcn_mfma_f32_16x16x32_bf16(a, b, acc[j], 0, 0, 0);
        }
#pragma unroll
        for (int j = 0; j < 4; ++j) issueS(nxp, j);
        asm volatile("s_waitcnt vmcnt(4)" ::: "memory");
#pragma unroll
        for (int j = 4; j < 8; ++j) {
            bf16x8 b = *(const bf16x8*)&ring[wid][j][l * 8];
            acc[j] = __builtin_amdgcn_mfma_f32_16x16x32_bf16(a, b, acc[j], 0, 0, 0);
        }
#pragma unroll
        for (int j = 4; j < 8; ++j) issueS(nxp, j);
    };

    // ---- main loop: compute h_t for t = 2..T ----
    for (int t = 2; t <= T; ++t) {
        const short* curb = hbuf[(t - 1) & 1];
        short*       nxtb = hbuf[t & 1];

        phaseR0(curb);
        phaseR(ic<1>{}, curb);
        phaseR(ic<2>{}, curb);
        phaseR(ic<3>{}, curb);
        phaseP(curb);
        phaseS(ic<5>{}, ic<1>{}, curb);   // consume kk5, prefetch kk6
        phaseS(ic<6>{}, ic<2>{}, curb);   // consume kk6, prefetch kk7
        phaseS(ic<7>{}, ic<0>{}, curb);   // consume kk7, prefetch next-step kk5

        update_write(nxtb, H + ((size_t)(t - 1) * Btot + row0) * 256);

        // raw barrier: h LDS writes visible; ring prefetch stays in flight
        asm volatile("s_waitcnt lgkmcnt(0)" ::: "memory");
        __builtin_amdgcn_sched_barrier(0);
        __builtin_amdgcn_s_barrier();
    }
}

// ---------------------------------------------------------------------------
// Y[s][b][:] = H[s][b][:] @ Wout^T + b_out, IN PLACE (H bf16 row = 512 B =
// Y f32 row). Each wave reads only its own 32 rows then overwrites them.
// ---------------------------------------------------------------------------
__global__ __launch_bounds__(512) void out_gemm(
    const unsigned short* __restrict__ Wout_p,
    const float* __restrict__ b_out,
    float* __restrict__ Y)
{
    const int tid = threadIdx.x;
    const int l   = tid & 63;
    const int w   = tid >> 6;
    const int l15 = l & 15;
    const int g4  = l >> 4;
    const size_t rw0 = (size_t)blockIdx.x * 256 + w * 32;
    const unsigned short* Hp = (const unsigned short*)Y;

    bf16x8 a[2][8];
#pragma unroll
    for (int rt = 0; rt < 2; ++rt)
#pragma unroll
        for (int kk = 0; kk < 8; ++kk) {
            const unsigned short* src = Hp + (rw0 + rt * 16 + l15) * 256 + kk * 32 + 4 * g4;
            s16x4 lo = *(const s16x4*)(src);
            s16x4 hi = *(const s16x4*)(src + 16);
            bf16x8 v;
            v[0] = lo[0]; v[1] = lo[1]; v[2] = lo[2]; v[3] = lo[3];
            v[4] = hi[0]; v[5] = hi[1]; v[6] = hi[2]; v[7] = hi[3];
            a[rt][kk] = v;
        }

    f32x4 acc[2][8];
#pragma unroll
    for (int rt = 0; rt < 2; ++rt)
#pragma unroll
        for (int wv = 0; wv < 8; ++wv) acc[rt][wv] = (f32x4){0.f, 0.f, 0.f, 0.f};

#pragma unroll
    for (int kk = 0; kk < 8; ++kk)
#pragma unroll
        for (int wv = 0; wv < 8; ++wv) {
            bf16x8 wf = *(const bf16x8*)(Wout_p + ((size_t)(wv * 8 + kk) * 64 + l) * 8);
            acc[0][wv] = __builtin_amdgcn_mfma_f32_16x16x32_bf16(a[0][kk], wf, acc[0][wv], 0, 0, 0);
            acc[1][wv] = __builtin_amdgcn_mfma_f32_16x16x32_bf16(a[1][kk], wf, acc[1][wv], 0, 0, 0);
        }

#pragma unroll
    for (int wv = 0; wv < 8; ++wv) {
        float by = b_out[wv * 16 + l15];
#pragma unroll
        for (int rt = 0; rt < 2; ++rt)
#pragma unroll
            for (int i = 0; i < 4; ++i)
                Y[(rw0 + rt * 16 + 4 * g4 + i) * 128 + wv * 16 + l15] = acc[rt][wv][i] + by;
    }
}

extern "C" void kernel_launch(void* const* d_in, const int* in_sizes, int n_in,
                              void* d_out, int out_size, void* d_ws, size_t ws_size,
                              hipStream_t stream) {
    const float* C     = (const float*)d_in[0];
    const float* W_ih  = (const float*)d_in[1];
    const float* W_hh  = (const float*)d_in[2];
    const float* b_ih  = (const float*)d_in[3];
    const float* b_hh  = (const float*)d_in[4];
    const float* W_out = (const float*)d_in[5];
    const float* b_out = (const float*)d_in[6];

    const int H    = 256;
    const int Btot = in_sizes[0] / H;     // 2048
    const int O    = in_sizes[5] / H;     // 128
    const int T    = out_size / (Btot * O);

    char* ws = (char*)d_ws;
    unsigned short* Whh_p  = (unsigned short*)(ws);                 // 512 KB
    unsigned short* Wih_p  = (unsigned short*)(ws + (512 << 10));   // 512 KB
    unsigned short* Wout_p = (unsigned short*)(ws + (1024 << 10));  // 64 KB
    unsigned short* rep    = (unsigned short*)(ws + (1088 << 10));  // copies

    const size_t copy_bytes = 196608;     // 192 KB
    size_t avail = (ws_size > (1088u << 10)) ? ws_size - (1088u << 10) : 0;
    int ncopies = (int)(avail / copy_bytes);
    if (ncopies > 64) ncopies = 64;       // 2 same-XCD readers per copy
    if (ncopies < 1)  ncopies = 1;

    hipLaunchKernelGGL(pack_w_big, dim3(128), dim3(256), 0, stream, W_hh, Whh_p);
    hipLaunchKernelGGL(pack_w_big, dim3(128), dim3(256), 0, stream, W_ih, Wih_p);
    hipLaunchKernelGGL(pack_w_out, dim3(16),  dim3(256), 0, stream, W_out, Wout_p);
    hipLaunchKernelGGL(replicate_stream, dim3(ncopies * 48), dim3(256), 0, stream,
                       Whh_p, rep);
    hipLaunchKernelGGL(lstm_gates, dim3(Btot / 16), dim3(512), 0, stream,
                       C, Wih_p, Whh_p, rep, b_ih, b_hh,
                       (unsigned short*)d_out, T, Btot, ncopies);
    hipLaunchKernelGGL(out_gemm, dim3((T * Btot) / 256), dim3(512), 0, stream,
                       Wout_p, b_out, (float*)d_out);
}

// Round 10
// 681.318 us; speedup vs baseline: 1.4317x; 1.3906x over previous
//
#include <hip/hip_runtime.h>
#include <hip/hip_bf16.h>

typedef __attribute__((ext_vector_type(8))) short  bf16x8;
typedef __attribute__((ext_vector_type(4))) short  s16x4;
typedef __attribute__((ext_vector_type(4))) float  f32x4;
typedef __attribute__((ext_vector_type(4))) unsigned int u32x4;

#define LOG2E 1.44269504088896340736f
template<int N> struct ic { static constexpr int v = N; };

__device__ __forceinline__ unsigned short f2bf(float x) {
    union { float f; unsigned int u; } v; v.f = x;
    unsigned int u = v.u;
    u += 0x7fffu + ((u >> 16) & 1u);          // round-to-nearest-even
    return (unsigned short)(u >> 16);
}
__device__ __forceinline__ float fast_sigmoid(float x) {
    float e = __builtin_amdgcn_exp2f(-LOG2E * x);
    return __builtin_amdgcn_rcpf(1.0f + e);
}
__device__ __forceinline__ float fast_tanh(float x) {
    float e = __builtin_amdgcn_exp2f(2.0f * LOG2E * x);
    return 1.0f - 2.0f * __builtin_amdgcn_rcpf(1.0f + e);
}

// ---------------------------------------------------------------------------
// Pack [1024 x 256] fp32 weight into bf16 MFMA-B-fragment-major layout.
//   fid = w*64 + kk*8 + j ; dst[(fid*64+lane)*8+e] = bf16(W[R][k])
//   R = g*256 + w*32 + tn*16 + (lane&15), j = g*2+tn
//   k = kk*32 + 4*(lane>>4) + (e&3) + 16*(e>>2)
// ---------------------------------------------------------------------------
__global__ void pack_w_big(const float* __restrict__ W, unsigned short* __restrict__ dst) {
    int idx  = blockIdx.x * 256 + threadIdx.x;   // 0..32767
    int lane = idx & 63;
    int fid  = idx >> 6;                         // 0..511
    int j    = fid & 7;
    int kk   = (fid >> 3) & 7;
    int w    = fid >> 6;
    int g    = j >> 1, tn = j & 1;
    int R    = g * 256 + w * 32 + tn * 16 + (lane & 15);
    int kb   = kk * 32 + 4 * (lane >> 4);
    const float* src = W + (size_t)R * 256 + kb;
    union { unsigned short s[8]; u32x4 v; } u;
#pragma unroll
    for (int e = 0; e < 8; ++e) {
        int k = (e & 3) + 16 * (e >> 2);
        u.s[e] = f2bf(src[k]);
    }
    *(u32x4*)(dst + (size_t)idx * 8) = u.v;
}

// W_out [128 x 256]: fid = wv*8 + kk, R = wv*16 + (lane&15)
__global__ void pack_w_out(const float* __restrict__ W, unsigned short* __restrict__ dst) {
    int idx  = blockIdx.x * 256 + threadIdx.x;   // 0..4095
    int lane = idx & 63;
    int fid  = idx >> 6;
    int kk   = fid & 7;
    int wv   = fid >> 3;
    int R    = wv * 16 + (lane & 15);
    int kb   = kk * 32 + 4 * (lane >> 4);
    const float* src = W + (size_t)R * 256 + kb;
    union { unsigned short s[8]; u32x4 v; } u;
#pragma unroll
    for (int e = 0; e < 8; ++e) {
        int k = (e & 3) + 16 * (e >> 2);
        u.s[e] = f2bf(src[k]);
    }
    *(u32x4*)(dst + (size_t)idx * 8) = u.v;
}

// ---------------------------------------------------------------------------
// Gates-only persistent LSTM. 128 blocks x 512 thr (8 waves). Wave w owns
// gate strip [w*32,+32) x {i,f,g,o}. h_t kept in swizzled LDS; ONE coalesced
// 16B NT store per thread per step writes h_{t-1} to H (= d_out, in place).
// Whh: kk0..3 compiler-resident, kk4 LDS-parked, kk5..7 streamed via
// global_load_lds ring. vmcnt is counted so in-loop waits never drain the
// single trailing h-store (S5 waits vmcnt(5); S6/S7 vmcnt(4)).
// ---------------------------------------------------------------------------
__global__ __launch_bounds__(512) __attribute__((amdgpu_waves_per_eu(2, 2)))
void lstm_gates(const float* __restrict__ C,
                const unsigned short* __restrict__ Wih_p,
                const unsigned short* __restrict__ Whh_p,
                const float* __restrict__ b_ih,
                const float* __restrict__ b_hh,
                unsigned short* __restrict__ H,
                int T, int Btot)
{
    __shared__ short hbuf[2][4096];     // 16 KB h double-buffer
    __shared__ short park[8][8][512];   // 64 KB kk4 B-frags (per wave)
    __shared__ short ring[8][8][512];   // 64 KB stream ring: slot j <-> frag j

    const int tid  = threadIdx.x;
    const int l    = tid & 63;
    const int wid  = tid >> 6;
    const int l15  = l & 15;
    const int g4   = l >> 4;
    const int row0 = blockIdx.x * 16;

    const unsigned short* wib = Wih_p + (size_t)wid * 32768;
    const unsigned short* whb = Whh_p + (size_t)wid * 32768;

    // ---- stage C tile -> hbuf[0] (bf16, swizzled 8B slots) ----
    {
        int r  = tid >> 5;
        int cb = tid & 31;
        const float* src = C + (size_t)(row0 + r) * 256 + cb * 8;
        float4 f0 = *(const float4*)(src);
        float4 f1 = *(const float4*)(src + 4);
        int m  = 9 * (r & 7);
        int s0 = cb * 2;
        short* hb = hbuf[0] + r * 256;
        union { unsigned short s[4]; unsigned long long v; } p0, p1;
        p0.s[0] = f2bf(f0.x); p0.s[1] = f2bf(f0.y); p0.s[2] = f2bf(f0.z); p0.s[3] = f2bf(f0.w);
        p1.s[0] = f2bf(f1.x); p1.s[1] = f2bf(f1.y); p1.s[2] = f2bf(f1.z); p1.s[3] = f2bf(f1.w);
        *(unsigned long long*)(hb + ((s0 ^ m) * 4))       = p0.v;
        *(unsigned long long*)(hb + (((s0 + 1) ^ m) * 4)) = p1.v;
    }

    auto issueP = [&](int j) {
        const unsigned short* src = whb + (((size_t)4 * 8 + j) * 64 + l) * 8;
        __builtin_amdgcn_global_load_lds(
            (const __attribute__((address_space(1))) void*)src,
            (__attribute__((address_space(3))) void*)&park[wid][j][0], 16, 0, 0);
    };
    auto issueS = [&](int kk, int j) {   // kk in {5,6,7}
        const unsigned short* src = whb + (((size_t)kk * 8 + j) * 64 + l) * 8;
        __builtin_amdgcn_global_load_lds(
            (const __attribute__((address_space(1))) void*)src,
            (__attribute__((address_space(3))) void*)&ring[wid][j][0], 16, 0, 0);
    };
#pragma unroll
    for (int j = 0; j < 8; ++j) issueP(j);
#pragma unroll
    for (int j = 0; j < 8; ++j) issueS(5, j);

    // A-frag loader: row = l&15, k = kk*32 + 4*(l>>4) + {0..3,16..19}
    const int msw = 9 * (l15 & 7);
    auto loadA = [&](const short* buf, int kk) -> bf16x8 {
        int slo = kk * 8 + g4;
        const short* base = buf + l15 * 256;
        s16x4 lo = *(const s16x4*)(base + ((slo ^ msw) * 4));
        s16x4 hi = *(const s16x4*)(base + (((slo + 4) ^ msw) * 4));
        bf16x8 a;
        a[0] = lo[0]; a[1] = lo[1]; a[2] = lo[2]; a[3] = lo[3];
        a[4] = hi[0]; a[5] = hi[1]; a[6] = hi[2]; a[7] = hi[3];
        return a;
    };
    auto loadB = [&](const unsigned short* wb, int kk, int j) -> bf16x8 {
        return *(const bf16x8*)(wb + (((size_t)kk * 8 + j) * 64 + l) * 8);
    };

    __syncthreads();   // C tile + park + ring(kk5) staged (one-time drain)

    // ---- acc = x_gates = C @ Wih^T + b_ih + b_hh ----
    f32x4 acc[8];
#pragma unroll
    for (int j = 0; j < 8; ++j) acc[j] = (f32x4){0.f, 0.f, 0.f, 0.f};
#pragma unroll
    for (int kk = 0; kk < 8; ++kk) {
        bf16x8 a = loadA(hbuf[0], kk);
#pragma unroll
        for (int j = 0; j < 8; ++j)
            acc[j] = __builtin_amdgcn_mfma_f32_16x16x32_bf16(a, loadB(wib, kk, j), acc[j], 0, 0, 0);
    }
#pragma unroll
    for (int j = 0; j < 8; ++j) {
        int g = j >> 1, tn = j & 1;
        int col = g * 256 + wid * 32 + tn * 16 + l15;
        float bias = b_ih[col] + b_hh[col];
        acc[j] = acc[j] + bias;
    }
    // pack x_gates to bf16 (persistent, 16 regs)
    unsigned xgp[16];
#pragma unroll
    for (int j = 0; j < 8; ++j) {
        xgp[2 * j]     = (unsigned)f2bf(acc[j][0]) | ((unsigned)f2bf(acc[j][1]) << 16);
        xgp[2 * j + 1] = (unsigned)f2bf(acc[j][2]) | ((unsigned)f2bf(acc[j][3]) << 16);
    }
    auto xgu = [&](int j) -> f32x4 {
        union { unsigned u; float f; } c0, c1, c2, c3;
        unsigned u0 = xgp[2 * j], u1 = xgp[2 * j + 1];
        c0.u = u0 << 16; c1.u = u0 & 0xffff0000u;
        c2.u = u1 << 16; c3.u = u1 & 0xffff0000u;
        return (f32x4){c0.f, c1.f, c2.f, c3.f};
    };

    // ---- Whh kk0..3 resident (compiler-managed VGPR/AGPR) ----
    bf16x8 whr[4][8];
#pragma unroll
    for (int kk = 0; kk < 4; ++kk)
#pragma unroll
        for (int j = 0; j < 8; ++j) whr[kk][j] = loadB(whb, kk, j);

    float cst[8];
#pragma unroll
    for (int i = 0; i < 8; ++i) cst[i] = 0.f;

    // cell update -> h into nxtb (swizzled LDS ONLY — no global stores here)
    auto update_write = [&](short* nxtb) {
#pragma unroll
        for (int tn = 0; tn < 2; ++tn) {
#pragma unroll
            for (int rr = 0; rr < 4; ++rr) {
                float iv = fast_sigmoid(acc[0 + tn][rr]);
                float fv = fast_sigmoid(acc[2 + tn][rr]);
                float gv = fast_tanh(acc[4 + tn][rr]);
                float ov = fast_sigmoid(acc[6 + tn][rr]);
                float cn = fv * cst[tn * 4 + rr] + iv * gv;
                cst[tn * 4 + rr] = cn;
                float hn = ov * fast_tanh(cn);
                unsigned short hb = f2bf(hn);
                int row = 4 * g4 + rr;
                int col = wid * 32 + tn * 16 + l15;
                int ps  = (col >> 2) ^ (9 * (row & 7));
                nxtb[row * 256 + ps * 4 + (col & 3)] = (short)hb;
            }
        }
    };

    // coalesced h readback: ONE 16B NT store per thread (unswizzle from LDS)
    auto store_h = [&](const short* srcb, unsigned short* dst) {
        int r  = tid >> 5;          // 0..15
        int cb = tid & 31;          // 8-short block
        int m  = 9 * (r & 7);
        const short* hb = srcb + r * 256;
        union { s16x4 h[2]; u32x4 v; } u;
        u.h[0] = *(const s16x4*)(hb + (((cb * 2)     ^ m) * 4));
        u.h[1] = *(const s16x4*)(hb + (((cb * 2 + 1) ^ m) * 4));
        __builtin_nontemporal_store(u.v, (u32x4*)(dst + (size_t)r * 256 + cb * 8));
    };

    // ---- t = 1: gates = x_gates (h0 = 0); h1 -> hbuf[1] (LDS only) ----
    update_write(hbuf[1]);
    __syncthreads();

    // ---- phase lambdas ----
    auto phaseR0 = [&](const short* curb) {
        bf16x8 a = loadA(curb, 0);
#pragma unroll
        for (int j = 0; j < 8; ++j)
            acc[j] = __builtin_amdgcn_mfma_f32_16x16x32_bf16(a, whr[0][j], xgu(j), 0, 0, 0);
    };
    auto phaseR = [&](auto KK, const short* curb) {
        constexpr int kk = decltype(KK)::v;
        bf16x8 a = loadA(curb, kk);
#pragma unroll
        for (int j = 0; j < 8; ++j)
            acc[j] = __builtin_amdgcn_mfma_f32_16x16x32_bf16(a, whr[kk][j], acc[j], 0, 0, 0);
    };
    auto phaseP = [&](const short* curb) {
        bf16x8 a = loadA(curb, 4);
#pragma unroll
        for (int j = 0; j < 8; ++j) {
            bf16x8 b = *(const bf16x8*)&park[wid][j][l * 8];
            acc[j] = __builtin_amdgcn_mfma_f32_16x16x32_bf16(a, b, acc[j], 0, 0, 0);
        }
    };
    // W = vmcnt tolerance (5 while the trailing h-store may be outstanding,
    // 4 afterwards). Queue accounting in the round notes.
    auto phaseS = [&](auto KK, auto NX, auto WT, const short* curb) {
        constexpr int kk = decltype(KK)::v;      // consumed slice (5,6,7)
        constexpr int nx = decltype(NX)::v;      // slice to issue next
        constexpr int wt = decltype(WT)::v;
        bf16x8 a = loadA(curb, kk);
        if constexpr (wt == 5) asm volatile("s_waitcnt vmcnt(5)" ::: "memory");
        else                   asm volatile("s_waitcnt vmcnt(4)" ::: "memory");
#pragma unroll
        for (int j = 0; j < 4; ++j) {
            bf16x8 b = *(const bf16x8*)&ring[wid][j][l * 8];
            acc[j] = __builtin_amdgcn_mfma_f32_16x16x32_bf16(a, b, acc[j], 0, 0, 0);
        }
#pragma unroll
        for (int j = 0; j < 4; ++j) issueS(nx, j);
        if constexpr (wt == 5) asm volatile("s_waitcnt vmcnt(5)" ::: "memory");
        else                   asm volatile("s_waitcnt vmcnt(4)" ::: "memory");
#pragma unroll
        for (int j = 4; j < 8; ++j) {
            bf16x8 b = *(const bf16x8*)&ring[wid][j][l * 8];
            acc[j] = __builtin_amdgcn_mfma_f32_16x16x32_bf16(a, b, acc[j], 0, 0, 0);
        }
#pragma unroll
        for (int j = 4; j < 8; ++j) issueS(nx, j);
    };

    // ---- main loop: compute h_t for t = 2..T; store h_{t-1} -> H[t-2] ----
    for (int t = 2; t <= T; ++t) {
        const short* curb = hbuf[(t - 1) & 1];
        short*       nxtb = hbuf[t & 1];

        phaseR0(curb);
        phaseR(ic<1>{}, curb);
        phaseR(ic<2>{}, curb);
        phaseR(ic<3>{}, curb);
        phaseP(curb);
        phaseS(ic<5>{}, ic<6>{}, ic<5>{}, curb);   // consume kk5, issue kk6
        phaseS(ic<6>{}, ic<7>{}, ic<4>{}, curb);   // consume kk6, issue kk7
        phaseS(ic<7>{}, ic<5>{}, ic<4>{}, curb);   // consume kk7, issue next kk5

        // h_{t-1} -> H[t-2]: issued AFTER the kk5 prefetch, so the queue at
        // the next step's S5 is exactly [kk5 x8, store x1]
        store_h(curb, H + ((size_t)(t - 2) * Btot + row0) * 256);

        update_write(nxtb);

        // raw barrier: h LDS writes visible; loads + h-store stay in flight
        asm volatile("s_waitcnt lgkmcnt(0)" ::: "memory");
        __builtin_amdgcn_sched_barrier(0);
        __builtin_amdgcn_s_barrier();
    }

    // ---- epilogue: h_T -> H[T-1] ----
    store_h(hbuf[T & 1], H + ((size_t)(T - 1) * Btot + row0) * 256);
}

// ---------------------------------------------------------------------------
// Y[s][b][:] = H[s][b][:] @ Wout^T + b_out, IN PLACE (H bf16 row = 512 B =
// Y f32 row). Each wave reads only its own 32 rows then overwrites them.
// ---------------------------------------------------------------------------
__global__ __launch_bounds__(512) void out_gemm(
    const unsigned short* __restrict__ Wout_p,
    const float* __restrict__ b_out,
    float* __restrict__ Y)
{
    const int tid = threadIdx.x;
    const int l   = tid & 63;
    const int w   = tid >> 6;
    const int l15 = l & 15;
    const int g4  = l >> 4;
    const size_t rw0 = (size_t)blockIdx.x * 256 + w * 32;
    const unsigned short* Hp = (const unsigned short*)Y;

    bf16x8 a[2][8];
#pragma unroll
    for (int rt = 0; rt < 2; ++rt)
#pragma unroll
        for (int kk = 0; kk < 8; ++kk) {
            const unsigned short* src = Hp + (rw0 + rt * 16 + l15) * 256 + kk * 32 + 4 * g4;
            s16x4 lo = *(const s16x4*)(src);
            s16x4 hi = *(const s16x4*)(src + 16);
            bf16x8 v;
            v[0] = lo[0]; v[1] = lo[1]; v[2] = lo[2]; v[3] = lo[3];
            v[4] = hi[0]; v[5] = hi[1]; v[6] = hi[2]; v[7] = hi[3];
            a[rt][kk] = v;
        }

    f32x4 acc[2][8];
#pragma unroll
    for (int rt = 0; rt < 2; ++rt)
#pragma unroll
        for (int wv = 0; wv < 8; ++wv) acc[rt][wv] = (f32x4){0.f, 0.f, 0.f, 0.f};

#pragma unroll
    for (int kk = 0; kk < 8; ++kk)
#pragma unroll
        for (int wv = 0; wv < 8; ++wv) {
            bf16x8 wf = *(const bf16x8*)(Wout_p + ((size_t)(wv * 8 + kk) * 64 + l) * 8);
            acc[0][wv] = __builtin_amdgcn_mfma_f32_16x16x32_bf16(a[0][kk], wf, acc[0][wv], 0, 0, 0);
            acc[1][wv] = __builtin_amdgcn_mfma_f32_16x16x32_bf16(a[1][kk], wf, acc[1][wv], 0, 0, 0);
        }

#pragma unroll
    for (int wv = 0; wv < 8; ++wv) {
        float by = b_out[wv * 16 + l15];
#pragma unroll
        for (int rt = 0; rt < 2; ++rt)
#pragma unroll
            for (int i = 0; i < 4; ++i)
                Y[(rw0 + rt * 16 + 4 * g4 + i) * 128 + wv * 16 + l15] = acc[rt][wv][i] + by;
    }
}

extern "C" void kernel_launch(void* const* d_in, const int* in_sizes, int n_in,
                              void* d_out, int out_size, void* d_ws, size_t ws_size,
                              hipStream_t stream) {
    const float* C     = (const float*)d_in[0];
    const float* W_ih  = (const float*)d_in[1];
    const float* W_hh  = (const float*)d_in[2];
    const float* b_ih  = (const float*)d_in[3];
    const float* b_hh  = (const float*)d_in[4];
    const float* W_out = (const float*)d_in[5];
    const float* b_out = (const float*)d_in[6];

    const int H    = 256;
    const int Btot = in_sizes[0] / H;     // 2048
    const int O    = in_sizes[5] / H;     // 128
    const int T    = out_size / (Btot * O);

    unsigned short* Whh_p  = (unsigned short*)d_ws;          // 512 KB
    unsigned short* Wih_p  = Whh_p + (1 << 18);              // 512 KB
    unsigned short* Wout_p = Wih_p + (1 << 18);              // 64 KB

    hipLaunchKernelGGL(pack_w_big, dim3(128), dim3(256), 0, stream, W_hh, Whh_p);
    hipLaunchKernelGGL(pack_w_big, dim3(128), dim3(256), 0, stream, W_ih, Wih_p);
    hipLaunchKernelGGL(pack_w_out, dim3(16),  dim3(256), 0, stream, W_out, Wout_p);
    hipLaunchKernelGGL(lstm_gates, dim3(Btot / 16), dim3(512), 0, stream,
                       C, Wih_p, Whh_p, b_ih, b_hh,
                       (unsigned short*)d_out, T, Btot);
    hipLaunchKernelGGL(out_gemm, dim3((T * Btot) / 256), dim3(512), 0, stream,
                       Wout_p, b_out, (float*)d_out);
}